// Round 3
// baseline (278.663 us; speedup 1.0000x reference)
//
#include <hip/hip_runtime.h>

// DiffeomorphicTransform: scaling-and-squaring integration of a velocity field.
//   flow = velocity / 2^7
//   repeat 7x: flow = flow + trilinear_sample(flow, sample_grid + flow_perm)
// Volume: B=1, C=3, D=H=W=128, f32.
//
// R2: AoS float4 flow -> 8 dwordx4 gathers/voxel (was 24 scalar). 92->50us/step.
// R3: sample_grid is a broadcast meshgrid of 3 linspaces (separable). Extract
//     the 3x128 axis tables from the input ONCE (bit-identical values), stage
//     in LDS, and eliminate the 24 MB/step grid stream.

#define DD 128
#define HH 128
#define WW 128
#define NVOX (DD * HH * WW)          // 2,097,152
#define NELEM (3 * NVOX)             // 6,291,456
#define SCALE 63.5f                  // 0.5*(dim-1), same for x/y/z

// ---------------- axis-table extraction (runs once, 1 block) ----------------
// grid layout [D][H][W][3]; identity grid is broadcast => row (d=0,h=0) holds
// all x values, column (d=0,w=0) all y values, pillar (h=0,w=0) all z values.
__global__ void extract_tables_kernel(const float* __restrict__ grid,
                                      float* __restrict__ tbl) {
    int i = threadIdx.x;   // 384 threads
    if (i < 128) {
        tbl[i] = grid[3 * i + 0];                      // t_x[w]
    } else if (i < 256) {
        int h = i - 128;
        tbl[128 + h] = grid[(h * WW) * 3 + 1];         // t_y[h]
    } else if (i < 384) {
        int d = i - 256;
        tbl[256 + d] = grid[(d * HH * WW) * 3 + 2];    // t_z[d]
    }
}

// ---------------- init: flow0 = velocity/128, planar -> AoS ----------------
__global__ __launch_bounds__(256) void init_flow_aos_kernel(
    const float* __restrict__ vel, float4* __restrict__ flow) {
    int i = blockIdx.x * blockDim.x + threadIdx.x;
    if (i >= NVOX) return;
    float4 f;
    f.x = vel[i] * (1.0f / 128.0f);
    f.y = vel[NVOX + i] * (1.0f / 128.0f);
    f.z = vel[2 * NVOX + i] * (1.0f / 128.0f);
    f.w = 0.0f;
    flow[i] = f;
}

// ---------------- warp step ----------------
// USE_TBL: grid coords from LDS axis tables (no 24MB grid stream).
// PLANAR_OUT: final step writes planar f32 straight to d_out.
template <bool USE_TBL, bool PLANAR_OUT>
__global__ __launch_bounds__(256) void warp_step_aos_kernel(
    const float4* __restrict__ src,    // [NVOX] AoS flow
    const float* __restrict__ grid,    // [D][H][W][3] (if !USE_TBL)
    const float* __restrict__ tbl,     // [384] axis tables (if USE_TBL)
    float4* __restrict__ dst4,
    float* __restrict__ dstp) {
    __shared__ float s_tx[128], s_ty[128], s_tz[128];
    int tid = threadIdx.x;
    if (USE_TBL) {
        if (tid < 128) {
            s_tx[tid] = tbl[tid];
            s_tz[tid] = tbl[256 + tid];
        } else {
            s_ty[tid - 128] = tbl[128 + (tid - 128)];
        }
        __syncthreads();
    }

    int idx = blockIdx.x * blockDim.x + threadIdx.x;
    if (idx >= NVOX) return;

    float4 f = src[idx];

    float gx, gy, gz;
    if (USE_TBL) {
        int w = idx & 127;
        int h = (idx >> 7) & 127;
        int d = idx >> 14;
        gx = s_tx[w];
        gy = s_ty[h];
        gz = s_tz[d];
    } else {
        gx = grid[3 * idx + 0];
        gy = grid[3 * idx + 1];
        gz = grid[3 * idx + 2];
    }

    // Unnormalize (align_corners=True) — same op order as reference.
    float x = (gx + f.x + 1.0f) * SCALE;
    float y = (gy + f.y + 1.0f) * SCALE;
    float z = (gz + f.z + 1.0f) * SCALE;

    float x0f = floorf(x), y0f = floorf(y), z0f = floorf(z);
    float wx = x - x0f, wy = y - y0f, wz = z - z0f;
    float omx = 1.0f - wx, omy = 1.0f - wy, omz = 1.0f - wz;

    int x0 = min(max((int)x0f, 0), WW - 1);
    int x1 = min(max((int)x0f + 1, 0), WW - 1);
    int y0 = min(max((int)y0f, 0), HH - 1);
    int y1 = min(max((int)y0f + 1, 0), HH - 1);
    int z0 = min(max((int)z0f, 0), DD - 1);
    int z1 = min(max((int)z0f + 1, 0), DD - 1);

    const float4* r00 = src + (z0 * HH + y0) * WW;
    const float4* r01 = src + (z0 * HH + y1) * WW;
    const float4* r10 = src + (z1 * HH + y0) * WW;
    const float4* r11 = src + (z1 * HH + y1) * WW;

    float4 c000 = r00[x0], c001 = r00[x1];
    float4 c010 = r01[x0], c011 = r01[x1];
    float4 c100 = r10[x0], c101 = r10[x1];
    float4 c110 = r11[x0], c111 = r11[x1];

    float vx, vy, vzv;
    {
        float t, b;
        t = (c000.x * omx + c001.x * wx) * omy + (c010.x * omx + c011.x * wx) * wy;
        b = (c100.x * omx + c101.x * wx) * omy + (c110.x * omx + c111.x * wx) * wy;
        vx = t * omz + b * wz;
        t = (c000.y * omx + c001.y * wx) * omy + (c010.y * omx + c011.y * wx) * wy;
        b = (c100.y * omx + c101.y * wx) * omy + (c110.y * omx + c111.y * wx) * wy;
        vy = t * omz + b * wz;
        t = (c000.z * omx + c001.z * wx) * omy + (c010.z * omx + c011.z * wx) * wy;
        b = (c100.z * omx + c101.z * wx) * omy + (c110.z * omx + c111.z * wx) * wy;
        vzv = t * omz + b * wz;
    }

    if (PLANAR_OUT) {
        dstp[idx] = f.x + vx;
        dstp[NVOX + idx] = f.y + vy;
        dstp[2 * NVOX + idx] = f.z + vzv;
    } else {
        float4 o;
        o.x = f.x + vx;
        o.y = f.y + vy;
        o.z = f.z + vzv;
        o.w = 0.0f;
        dst4[idx] = o;
    }
}

// ---------------- planar fallback (tiny ws) ----------------
__global__ __launch_bounds__(256) void init_flow_kernel(
    const float* __restrict__ vel, float* __restrict__ flow) {
    int i = blockIdx.x * blockDim.x + threadIdx.x;
    if (i < NELEM) flow[i] = vel[i] * (1.0f / 128.0f);
}

__global__ __launch_bounds__(256) void warp_step_kernel(
    const float* __restrict__ src, const float* __restrict__ grid,
    float* __restrict__ dst) {
    int idx = blockIdx.x * blockDim.x + threadIdx.x;
    if (idx >= NVOX) return;

    float fx = src[idx];
    float fy = src[NVOX + idx];
    float fz = src[2 * NVOX + idx];
    float gx = grid[idx * 3 + 0];
    float gy = grid[idx * 3 + 1];
    float gz = grid[idx * 3 + 2];

    float x = (gx + fx + 1.0f) * SCALE;
    float y = (gy + fy + 1.0f) * SCALE;
    float z = (gz + fz + 1.0f) * SCALE;

    float x0f = floorf(x), y0f = floorf(y), z0f = floorf(z);
    float wx = x - x0f, wy = y - y0f, wz = z - z0f;

    int x0 = min(max((int)x0f, 0), WW - 1);
    int x1 = min(max((int)x0f + 1, 0), WW - 1);
    int y0 = min(max((int)y0f, 0), HH - 1);
    int y1 = min(max((int)y0f + 1, 0), HH - 1);
    int z0 = min(max((int)z0f, 0), DD - 1);
    int z1 = min(max((int)z0f + 1, 0), DD - 1);

    int o00 = (z0 * HH + y0) * WW;
    int o01 = (z0 * HH + y1) * WW;
    int o10 = (z1 * HH + y0) * WW;
    int o11 = (z1 * HH + y1) * WW;

    float omx = 1.0f - wx, omy = 1.0f - wy, omz = 1.0f - wz;

    #pragma unroll
    for (int c = 0; c < 3; ++c) {
        const float* p = src + c * NVOX;
        float c000 = p[o00 + x0], c001 = p[o00 + x1];
        float c010 = p[o01 + x0], c011 = p[o01 + x1];
        float c100 = p[o10 + x0], c101 = p[o10 + x1];
        float c110 = p[o11 + x0], c111 = p[o11 + x1];
        float top = (c000 * omx + c001 * wx) * omy + (c010 * omx + c011 * wx) * wy;
        float bot = (c100 * omx + c101 * wx) * omy + (c110 * omx + c111 * wx) * wy;
        float val = top * omz + bot * wz;
        float fcur = (c == 0) ? fx : ((c == 1) ? fy : fz);
        dst[c * NVOX + idx] = fcur + val;
    }
}

// ---------------- launch ----------------
extern "C" void kernel_launch(void* const* d_in, const int* in_sizes, int n_in,
                              void* d_out, int out_size, void* d_ws, size_t ws_size,
                              hipStream_t stream) {
    const float* vel  = (const float*)d_in[0];   // [1,3,128,128,128]
    const float* grid = (const float*)d_in[1];   // [1,128,128,128,3]
    float* out = (float*)d_out;

    const size_t aos_bytes = (size_t)NVOX * 16;  // 32 MiB per buffer
    const size_t tbl_bytes = 4096;               // 3*128 floats, padded

    if (ws_size >= 2 * aos_bytes + tbl_bytes) {
        // Fast path: axis tables + AoS ping-pong.
        float* tbl = (float*)d_ws;
        float4* A = (float4*)((char*)d_ws + tbl_bytes);
        float4* B = A + NVOX;

        extract_tables_kernel<<<1, 384, 0, stream>>>(grid, tbl);
        init_flow_aos_kernel<<<(NVOX + 255) / 256, 256, 0, stream>>>(vel, A);

        const float4* cur = A;
        for (int it = 0; it < 6; ++it) {
            float4* nxt = (it & 1) ? A : B;
            warp_step_aos_kernel<true, false><<<(NVOX + 255) / 256, 256, 0, stream>>>(
                cur, nullptr, tbl, nxt, nullptr);
            cur = nxt;
        }
        warp_step_aos_kernel<true, true><<<(NVOX + 255) / 256, 256, 0, stream>>>(
            cur, nullptr, tbl, nullptr, out);
    } else if (ws_size >= 2 * aos_bytes) {
        // AoS path with grid reads (R2).
        float4* A = (float4*)d_ws;
        float4* B = A + NVOX;
        init_flow_aos_kernel<<<(NVOX + 255) / 256, 256, 0, stream>>>(vel, A);
        const float4* cur = A;
        for (int it = 0; it < 6; ++it) {
            float4* nxt = (it & 1) ? A : B;
            warp_step_aos_kernel<false, false><<<(NVOX + 255) / 256, 256, 0, stream>>>(
                cur, grid, nullptr, nxt, nullptr);
            cur = nxt;
        }
        warp_step_aos_kernel<false, true><<<(NVOX + 255) / 256, 256, 0, stream>>>(
            cur, grid, nullptr, nullptr, out);
    } else {
        // Planar fallback (24 MiB ws).
        float* ws = (float*)d_ws;
        init_flow_kernel<<<(NELEM + 255) / 256, 256, 0, stream>>>(vel, ws);
        const float* cur = ws;
        for (int it = 0; it < 7; ++it) {
            float* nxt = (it & 1) ? ws : out;
            warp_step_kernel<<<(NVOX + 255) / 256, 256, 0, stream>>>(cur, grid, nxt);
            cur = nxt;
        }
    }
}

// Round 4
// 201.499 us; speedup vs baseline: 1.3829x; 1.3829x over previous
//
#include <hip/hip_runtime.h>

// DiffeomorphicTransform: scaling-and-squaring integration of a velocity field.
//   flow = velocity / 2^7
//   repeat 7x: flow = flow + trilinear_sample(flow, sample_grid + flow_perm)
// Volume: B=1, C=3, D=H=W=128, f32.
//
// R2: AoS float4 flow -> 8 dwordx4 gathers/voxel. 92->50us/step.
// R3: separable grid -> 3x128 LDS axis tables; -24MB/step fetch (neutral time
//     -> kernel is gather-TRANSACTION bound, not BW bound).
// R4: 2x2x2 supervoxel layout: one 128B cache line = one 2x2x2 float4 block.
//     A thread's 8 trilinear corners span ~3.4 lines instead of ~4.8 ->
//     ~30% fewer L1/L2 line transactions on the random late steps.
//     Thread gid = sv*8+phase keeps self-read/write perfectly coalesced.

#define DD 128
#define HH 128
#define WW 128
#define NVOX (DD * HH * WW)          // 2,097,152
#define NELEM (3 * NVOX)             // 6,291,456
#define SCALE 63.5f                  // 0.5*(dim-1), same for x/y/z

// float4-index of voxel (x,y,z) in the 2x2x2-blocked volume.
// supervoxel (x>>1,y>>1,z>>1) is a 128B-aligned block of 8 float4 slots,
// slot = (z&1)*4 + (y&1)*2 + (x&1).
__device__ __forceinline__ int blk_addr4(int xc, int yc, int zc) {
    return ((zc >> 1) << 15) + ((yc >> 1) << 9) + ((xc >> 1) << 3)
         + ((zc & 1) << 2) + ((yc & 1) << 1) + (xc & 1);
}

// ---------------- axis-table extraction (once, 1 block) ----------------
// grid [D][H][W][3] is a broadcast meshgrid: row (d=0,h=0) -> x table,
// (d=0,w=0) -> y table, (h=0,w=0) -> z table. Bit-identical values.
__global__ void extract_tables_kernel(const float* __restrict__ grid,
                                      float* __restrict__ tbl) {
    int i = threadIdx.x;   // 384 threads
    if (i < 128) {
        tbl[i] = grid[3 * i + 0];                      // t_x[w]
    } else if (i < 256) {
        int h = i - 128;
        tbl[128 + h] = grid[(h * WW) * 3 + 1];         // t_y[h]
    } else if (i < 384) {
        int d = i - 256;
        tbl[256 + d] = grid[(d * HH * WW) * 3 + 2];    // t_z[d]
    }
}

// ---------------- init: flow0 = velocity/128, planar -> blocked AoS ------
__global__ __launch_bounds__(256) void init_flow_blk_kernel(
    const float* __restrict__ vel, float4* __restrict__ flow) {
    int i = blockIdx.x * blockDim.x + threadIdx.x;   // linear voxel
    if (i >= NVOX) return;
    int x = i & 127, y = (i >> 7) & 127, z = i >> 14;
    float4 f;
    f.x = vel[i] * (1.0f / 128.0f);
    f.y = vel[NVOX + i] * (1.0f / 128.0f);
    f.z = vel[2 * NVOX + i] * (1.0f / 128.0f);
    f.w = 0.0f;
    flow[blk_addr4(x, y, z)] = f;   // scattered 16B stores (fire-and-forget)
}

// ---------------- warp step, blocked layout ----------------
template <bool PLANAR_OUT>
__global__ __launch_bounds__(256) void warp_step_blk_kernel(
    const float4* __restrict__ src,    // blocked AoS flow
    const float* __restrict__ tbl,     // [384] axis tables
    float4* __restrict__ dst4,         // blocked AoS out (if !PLANAR_OUT)
    float* __restrict__ dstp) {        // planar out (if PLANAR_OUT)
    __shared__ float s_tx[128], s_ty[128], s_tz[128];
    int tid = threadIdx.x;
    if (tid < 128) {
        s_tx[tid] = tbl[tid];
        s_tz[tid] = tbl[256 + tid];
    } else {
        s_ty[tid - 128] = tbl[tid];    // tbl[128 + (tid-128)]
    }
    __syncthreads();

    int gid = blockIdx.x * blockDim.x + threadIdx.x;
    if (gid >= NVOX) return;

    // gid = supervoxel*8 + phase  (bijective with blk_addr4(x,y,z))
    int phase = gid & 7;
    int sv = gid >> 3;
    int x = ((sv & 63) << 1) | (phase & 1);
    int y = (((sv >> 6) & 63) << 1) | ((phase >> 1) & 1);
    int z = ((sv >> 12) << 1) | ((phase >> 2) & 1);

    float4 f = src[gid];               // coalesced self-read

    // Unnormalize (align_corners=True) — same op order as reference.
    float xs = (s_tx[x] + f.x + 1.0f) * SCALE;
    float ys = (s_ty[y] + f.y + 1.0f) * SCALE;
    float zs = (s_tz[z] + f.z + 1.0f) * SCALE;

    float x0f = floorf(xs), y0f = floorf(ys), z0f = floorf(zs);
    float wx = xs - x0f, wy = ys - y0f, wz = zs - z0f;
    float omx = 1.0f - wx, omy = 1.0f - wy, omz = 1.0f - wz;

    int x0 = min(max((int)x0f, 0), WW - 1);
    int x1 = min(max((int)x0f + 1, 0), WW - 1);
    int y0 = min(max((int)y0f, 0), HH - 1);
    int y1 = min(max((int)y0f + 1, 0), HH - 1);
    int z0 = min(max((int)z0f, 0), DD - 1);
    int z1 = min(max((int)z0f + 1, 0), DD - 1);

    // 8 dwordx4 gathers; corners cluster into ~3.4 128B supervoxel lines.
    float4 c000 = src[blk_addr4(x0, y0, z0)];
    float4 c001 = src[blk_addr4(x1, y0, z0)];
    float4 c010 = src[blk_addr4(x0, y1, z0)];
    float4 c011 = src[blk_addr4(x1, y1, z0)];
    float4 c100 = src[blk_addr4(x0, y0, z1)];
    float4 c101 = src[blk_addr4(x1, y0, z1)];
    float4 c110 = src[blk_addr4(x0, y1, z1)];
    float4 c111 = src[blk_addr4(x1, y1, z1)];

    float vx, vy, vzv;
    {
        float t, b;
        t = (c000.x * omx + c001.x * wx) * omy + (c010.x * omx + c011.x * wx) * wy;
        b = (c100.x * omx + c101.x * wx) * omy + (c110.x * omx + c111.x * wx) * wy;
        vx = t * omz + b * wz;
        t = (c000.y * omx + c001.y * wx) * omy + (c010.y * omx + c011.y * wx) * wy;
        b = (c100.y * omx + c101.y * wx) * omy + (c110.y * omx + c111.y * wx) * wy;
        vy = t * omz + b * wz;
        t = (c000.z * omx + c001.z * wx) * omy + (c010.z * omx + c011.z * wx) * wy;
        b = (c100.z * omx + c101.z * wx) * omy + (c110.z * omx + c111.z * wx) * wy;
        vzv = t * omz + b * wz;
    }

    if (PLANAR_OUT) {
        int lin = (z * HH + y) * WW + x;
        dstp[lin] = f.x + vx;
        dstp[NVOX + lin] = f.y + vy;
        dstp[2 * NVOX + lin] = f.z + vzv;
    } else {
        float4 o;
        o.x = f.x + vx;
        o.y = f.y + vy;
        o.z = f.z + vzv;
        o.w = 0.0f;
        dst4[gid] = o;                 // coalesced
    }
}

// ---------------- linear-AoS path (R2/R3, fallback) ----------------
__global__ __launch_bounds__(256) void init_flow_aos_kernel(
    const float* __restrict__ vel, float4* __restrict__ flow) {
    int i = blockIdx.x * blockDim.x + threadIdx.x;
    if (i >= NVOX) return;
    float4 f;
    f.x = vel[i] * (1.0f / 128.0f);
    f.y = vel[NVOX + i] * (1.0f / 128.0f);
    f.z = vel[2 * NVOX + i] * (1.0f / 128.0f);
    f.w = 0.0f;
    flow[i] = f;
}

template <bool PLANAR_OUT>
__global__ __launch_bounds__(256) void warp_step_aos_kernel(
    const float4* __restrict__ src, const float* __restrict__ grid,
    float4* __restrict__ dst4, float* __restrict__ dstp) {
    int idx = blockIdx.x * blockDim.x + threadIdx.x;
    if (idx >= NVOX) return;

    float4 f = src[idx];
    float gx = grid[3 * idx + 0];
    float gy = grid[3 * idx + 1];
    float gz = grid[3 * idx + 2];

    float x = (gx + f.x + 1.0f) * SCALE;
    float y = (gy + f.y + 1.0f) * SCALE;
    float z = (gz + f.z + 1.0f) * SCALE;

    float x0f = floorf(x), y0f = floorf(y), z0f = floorf(z);
    float wx = x - x0f, wy = y - y0f, wz = z - z0f;
    float omx = 1.0f - wx, omy = 1.0f - wy, omz = 1.0f - wz;

    int x0 = min(max((int)x0f, 0), WW - 1);
    int x1 = min(max((int)x0f + 1, 0), WW - 1);
    int y0 = min(max((int)y0f, 0), HH - 1);
    int y1 = min(max((int)y0f + 1, 0), HH - 1);
    int z0 = min(max((int)z0f, 0), DD - 1);
    int z1 = min(max((int)z0f + 1, 0), DD - 1);

    const float4* r00 = src + (z0 * HH + y0) * WW;
    const float4* r01 = src + (z0 * HH + y1) * WW;
    const float4* r10 = src + (z1 * HH + y0) * WW;
    const float4* r11 = src + (z1 * HH + y1) * WW;

    float4 c000 = r00[x0], c001 = r00[x1];
    float4 c010 = r01[x0], c011 = r01[x1];
    float4 c100 = r10[x0], c101 = r10[x1];
    float4 c110 = r11[x0], c111 = r11[x1];

    float vx, vy, vzv;
    {
        float t, b;
        t = (c000.x * omx + c001.x * wx) * omy + (c010.x * omx + c011.x * wx) * wy;
        b = (c100.x * omx + c101.x * wx) * omy + (c110.x * omx + c111.x * wx) * wy;
        vx = t * omz + b * wz;
        t = (c000.y * omx + c001.y * wx) * omy + (c010.y * omx + c011.y * wx) * wy;
        b = (c100.y * omx + c101.y * wx) * omy + (c110.y * omx + c111.y * wx) * wy;
        vy = t * omz + b * wz;
        t = (c000.z * omx + c001.z * wx) * omy + (c010.z * omx + c011.z * wx) * wy;
        b = (c100.z * omx + c101.z * wx) * omy + (c110.z * omx + c111.z * wx) * wy;
        vzv = t * omz + b * wz;
    }

    if (PLANAR_OUT) {
        dstp[idx] = f.x + vx;
        dstp[NVOX + idx] = f.y + vy;
        dstp[2 * NVOX + idx] = f.z + vzv;
    } else {
        float4 o;
        o.x = f.x + vx; o.y = f.y + vy; o.z = f.z + vzv; o.w = 0.0f;
        dst4[idx] = o;
    }
}

// ---------------- planar fallback (tiny ws) ----------------
__global__ __launch_bounds__(256) void init_flow_kernel(
    const float* __restrict__ vel, float* __restrict__ flow) {
    int i = blockIdx.x * blockDim.x + threadIdx.x;
    if (i < NELEM) flow[i] = vel[i] * (1.0f / 128.0f);
}

__global__ __launch_bounds__(256) void warp_step_kernel(
    const float* __restrict__ src, const float* __restrict__ grid,
    float* __restrict__ dst) {
    int idx = blockIdx.x * blockDim.x + threadIdx.x;
    if (idx >= NVOX) return;

    float fx = src[idx];
    float fy = src[NVOX + idx];
    float fz = src[2 * NVOX + idx];
    float gx = grid[idx * 3 + 0];
    float gy = grid[idx * 3 + 1];
    float gz = grid[idx * 3 + 2];

    float x = (gx + fx + 1.0f) * SCALE;
    float y = (gy + fy + 1.0f) * SCALE;
    float z = (gz + fz + 1.0f) * SCALE;

    float x0f = floorf(x), y0f = floorf(y), z0f = floorf(z);
    float wx = x - x0f, wy = y - y0f, wz = z - z0f;

    int x0 = min(max((int)x0f, 0), WW - 1);
    int x1 = min(max((int)x0f + 1, 0), WW - 1);
    int y0 = min(max((int)y0f, 0), HH - 1);
    int y1 = min(max((int)y0f + 1, 0), HH - 1);
    int z0 = min(max((int)z0f, 0), DD - 1);
    int z1 = min(max((int)z0f + 1, 0), DD - 1);

    int o00 = (z0 * HH + y0) * WW;
    int o01 = (z0 * HH + y1) * WW;
    int o10 = (z1 * HH + y0) * WW;
    int o11 = (z1 * HH + y1) * WW;

    float omx = 1.0f - wx, omy = 1.0f - wy, omz = 1.0f - wz;

    #pragma unroll
    for (int c = 0; c < 3; ++c) {
        const float* p = src + c * NVOX;
        float c000 = p[o00 + x0], c001 = p[o00 + x1];
        float c010 = p[o01 + x0], c011 = p[o01 + x1];
        float c100 = p[o10 + x0], c101 = p[o10 + x1];
        float c110 = p[o11 + x0], c111 = p[o11 + x1];
        float top = (c000 * omx + c001 * wx) * omy + (c010 * omx + c011 * wx) * wy;
        float bot = (c100 * omx + c101 * wx) * omy + (c110 * omx + c111 * wx) * wy;
        float val = top * omz + bot * wz;
        float fcur = (c == 0) ? fx : ((c == 1) ? fy : fz);
        dst[c * NVOX + idx] = fcur + val;
    }
}

// ---------------- launch ----------------
extern "C" void kernel_launch(void* const* d_in, const int* in_sizes, int n_in,
                              void* d_out, int out_size, void* d_ws, size_t ws_size,
                              hipStream_t stream) {
    const float* vel  = (const float*)d_in[0];   // [1,3,128,128,128]
    const float* grid = (const float*)d_in[1];   // [1,128,128,128,3]
    float* out = (float*)d_out;

    const size_t aos_bytes = (size_t)NVOX * 16;  // 32 MiB per buffer
    const size_t tbl_bytes = 4096;               // 3*128 floats, padded

    if (ws_size >= 2 * aos_bytes + tbl_bytes) {
        // Fast path: axis tables + 2x2x2-blocked AoS ping-pong.
        float* tbl = (float*)d_ws;
        float4* A = (float4*)((char*)d_ws + tbl_bytes);
        float4* B = A + NVOX;

        extract_tables_kernel<<<1, 384, 0, stream>>>(grid, tbl);
        init_flow_blk_kernel<<<(NVOX + 255) / 256, 256, 0, stream>>>(vel, A);

        const float4* cur = A;
        for (int it = 0; it < 6; ++it) {
            float4* nxt = (it & 1) ? A : B;
            warp_step_blk_kernel<false><<<(NVOX + 255) / 256, 256, 0, stream>>>(
                cur, tbl, nxt, nullptr);
            cur = nxt;
        }
        warp_step_blk_kernel<true><<<(NVOX + 255) / 256, 256, 0, stream>>>(
            cur, tbl, nullptr, out);
    } else if (ws_size >= 2 * aos_bytes) {
        // Linear AoS path with grid reads (R2).
        float4* A = (float4*)d_ws;
        float4* B = A + NVOX;
        init_flow_aos_kernel<<<(NVOX + 255) / 256, 256, 0, stream>>>(vel, A);
        const float4* cur = A;
        for (int it = 0; it < 6; ++it) {
            float4* nxt = (it & 1) ? A : B;
            warp_step_aos_kernel<false><<<(NVOX + 255) / 256, 256, 0, stream>>>(
                cur, grid, nxt, nullptr);
            cur = nxt;
        }
        warp_step_aos_kernel<true><<<(NVOX + 255) / 256, 256, 0, stream>>>(
            cur, grid, nullptr, out);
    } else {
        // Planar fallback (24 MiB ws).
        float* ws = (float*)d_ws;
        init_flow_kernel<<<(NELEM + 255) / 256, 256, 0, stream>>>(vel, ws);
        const float* cur = ws;
        for (int it = 0; it < 7; ++it) {
            float* nxt = (it & 1) ? ws : out;
            warp_step_kernel<<<(NVOX + 255) / 256, 256, 0, stream>>>(cur, grid, nxt);
            cur = nxt;
        }
    }
}